// Round 6
// baseline (276.047 us; speedup 1.0000x reference)
//
#include <hip/hip_runtime.h>
#include <math.h>

#define PRE_NMS 2000
#define POST_NMS 1000
#define IOU_T 0.7f
#define IMGSZ 800.0f
#define CAP 6144            // level-1 candidates per image (expected ~3600)
#define SORTN 2048          // level-2 refined candidates (expected ~2003)
#define NBINS 1024
#define NWORDS 32           // ceil(PRE_NMS/64)
#define NSLICE 16           // blocks per image for hist/compact
#define MROWS 2048          // padded row dim of transposed mask

typedef unsigned long long u64;

__device__ __forceinline__ unsigned key_of(float f) {
    unsigned u = __float_as_uint(f);
    return (u & 0x80000000u) ? ~u : (u | 0x80000000u);
}
__device__ __forceinline__ float inv_key(unsigned k) {
    unsigned u = (k & 0x80000000u) ? (k ^ 0x80000000u) : ~k;
    return __uint_as_float(u);
}

// ---- K1: level-1 histogram (10-bit), 16 slices/image, merge via global atomics
__global__ __launch_bounds__(256) void hist_kernel(
    const float* __restrict__ scores, int A, unsigned* __restrict__ ghist) {
  int b = blockIdx.x, slice = blockIdx.y;
  __shared__ unsigned h[NBINS];
  int tid = threadIdx.x;
  for (int i = tid; i < NBINS; i += 256) h[i] = 0;
  __syncthreads();
  int per = (A + NSLICE - 1) / NSLICE;
  int lo = slice * per, hi = min(lo + per, A);
  const float* sc = scores + (size_t)b * A;
  for (int i = lo + tid; i < hi; i += 256)
    atomicAdd(&h[key_of(sc[i]) >> 22], 1u);
  __syncthreads();
  for (int i = tid; i < NBINS; i += 256)
    if (h[i]) atomicAdd(&ghist[b * NBINS + i], h[i]);
}

// ---- K2: suffix-scan ghist, find level-1 threshold bin T1 ----
__global__ __launch_bounds__(1024) void thresh1_kernel(
    const unsigned* __restrict__ ghist, int* __restrict__ T1) {
  int b = blockIdx.x, tid = threadIdx.x;
  __shared__ unsigned tmp[NBINS];
  __shared__ int s_T;
  unsigned v = ghist[b * NBINS + tid];
  for (int d = 1; d < NBINS; d <<= 1) {
    tmp[tid] = v;
    __syncthreads();
    if (tid + d < NBINS) v += tmp[tid + d];
    __syncthreads();
  }
  tmp[tid] = v;   // count of keys with bin >= tid
  __syncthreads();
  unsigned nextv = (tid < NBINS - 1) ? tmp[tid + 1] : 0u;
  if (v >= PRE_NMS && nextv < PRE_NMS) s_T = tid;
  __syncthreads();
  if (tid == 0) T1[b] = s_T;
}

// ---- K3: compact candidates above T1 (two-phase, 1 atomic/block) ----------
__global__ __launch_bounds__(256) void compact_kernel(
    const float* __restrict__ scores, int A, const int* __restrict__ T1,
    u64* __restrict__ cand, int* __restrict__ cand_cnt) {
  int b = blockIdx.x, slice = blockIdx.y;
  int tid = threadIdx.x;
  int lane = tid & 63, wave = tid >> 6;
  int T = T1[b];
  int per = (A + NSLICE - 1) / NSLICE;
  int lo = slice * per, hi = min(lo + per, A);
  const float* sc = scores + (size_t)b * A;
  int cnt = 0;
  for (int i = lo + tid; i < hi; i += 256)
    cnt += ((int)(key_of(sc[i]) >> 22) >= T);
  int pfx = cnt;
  #pragma unroll
  for (int d = 1; d < 64; d <<= 1) {
    int t2 = __shfl_up(pfx, d, 64);
    if (lane >= d) pfx += t2;
  }
  __shared__ int s_wt[4];
  __shared__ int s_base;
  if (lane == 63) s_wt[wave] = pfx;
  __syncthreads();
  if (tid == 0) {
    int tot = s_wt[0] + s_wt[1] + s_wt[2] + s_wt[3];
    int acc = 0;
    #pragma unroll
    for (int w2 = 0; w2 < 4; ++w2) { int t3 = s_wt[w2]; s_wt[w2] = acc; acc += t3; }
    s_base = atomicAdd(&cand_cnt[b], tot);
  }
  __syncthreads();
  int my_off = s_base + s_wt[wave] + (pfx - cnt);
  u64* cb = cand + (size_t)b * CAP;
  for (int i = lo + tid; i < hi; i += 256) {
    unsigned k = key_of(sc[i]);
    if ((int)(k >> 22) >= T) {
      if (my_off < CAP) cb[my_off] = ((u64)k << 32) | (unsigned)(~i);
      my_off++;
    }
  }
}

// ---- K4: refine + bitonic sort 2048 + FUSED decode of top-2000 ------------
__global__ __launch_bounds__(1024) void refine_sort_kernel(
    const u64* __restrict__ cand, const int* __restrict__ cand_cnt,
    const int* __restrict__ T1,
    const float* __restrict__ deltas, const float* __restrict__ anchors, int A,
    float* __restrict__ boxes, float* __restrict__ topk_logit) {
  int b = blockIdx.x, tid = threadIdx.x;
  int lane = tid & 63;
  __shared__ unsigned h2[NBINS];
  __shared__ unsigned tmp[NBINS];
  __shared__ u64 s[SORTN];
  __shared__ int s_above, s_sel, s_T2;
  int n = min(cand_cnt[b], CAP);
  const u64* cb = cand + (size_t)b * CAP;
  h2[tid] = 0;
  if (tid == 0) { s_above = 0; s_sel = 0; }
  __syncthreads();
  int T1v = T1[b];
  int loc = 0;
  for (int i = tid; i < n; i += 1024) {
    unsigned k = (unsigned)(cb[i] >> 32);
    if ((int)(k >> 22) > T1v) loc++;
    else atomicAdd(&h2[(k >> 12) & 1023], 1u);
  }
  for (int d = 32; d; d >>= 1) loc += __shfl_down(loc, d, 64);
  if (lane == 0 && loc) atomicAdd(&s_above, loc);
  __syncthreads();
  unsigned v = h2[tid];
  for (int d = 1; d < NBINS; d <<= 1) {
    tmp[tid] = v;
    __syncthreads();
    if (tid + d < NBINS) v += tmp[tid + d];
    __syncthreads();
  }
  tmp[tid] = v;
  __syncthreads();
  int above = s_above;
  unsigned nextv = (tid < NBINS - 1) ? tmp[tid + 1] : 0u;
  if (above + (int)v >= PRE_NMS && above + (int)nextv < PRE_NMS) s_T2 = tid;
  __syncthreads();
  unsigned thresh20 = ((unsigned)T1v << 10) | (unsigned)s_T2;
  for (int i = tid; i < SORTN; i += 1024) s[i] = 0ULL;
  __syncthreads();
  for (int i = tid; i < n; i += 1024) {
    u64 cv = cb[i];
    if ((unsigned)(cv >> 44) >= thresh20) {
      int pos = atomicAdd(&s_sel, 1);
      if (pos < SORTN) s[pos] = cv;
    }
  }
  __syncthreads();
  for (int k = 2; k <= SORTN; k <<= 1) {
    for (int j = k >> 1; j > 0; j >>= 1) {
      for (int i = tid; i < SORTN; i += 1024) {
        int l = i ^ j;
        if (l > i) {
          u64 a = s[i], c2 = s[l];
          bool desc = ((i & k) == 0);
          if (desc ? (a < c2) : (a > c2)) { s[i] = c2; s[l] = a; }
        }
      }
      __syncthreads();
    }
  }
  // fused decode (non-contracted fp32, matches numpy op-by-op)
  const float CLIP = 4.135166556742356f;  // log(1000/16)
  for (int i = tid; i < PRE_NMS; i += 1024) {
    u64 v2 = s[i];
    int a = (int)(~(unsigned)v2);
    topk_logit[b * PRE_NMS + i] = inv_key((unsigned)(v2 >> 32));
    float4 dl = ((const float4*)deltas)[(size_t)b * A + a];
    float4 an = ((const float4*)anchors)[a];
    float wa = __fsub_rn(an.z, an.x);
    float ha = __fsub_rn(an.w, an.y);
    float cxa = __fadd_rn(an.x, __fmul_rn(0.5f, wa));
    float cya = __fadd_rn(an.y, __fmul_rn(0.5f, ha));
    float dw = fminf(dl.z, CLIP), dh = fminf(dl.w, CLIP);
    float cx = __fadd_rn(__fmul_rn(dl.x, wa), cxa);
    float cy = __fadd_rn(__fmul_rn(dl.y, ha), cya);
    float w2 = __fmul_rn((float)exp((double)dw), wa);
    float h2f = __fmul_rn((float)exp((double)dh), ha);
    float x1 = __fsub_rn(cx, __fmul_rn(0.5f, w2));
    float y1 = __fsub_rn(cy, __fmul_rn(0.5f, h2f));
    float x2 = __fadd_rn(cx, __fmul_rn(0.5f, w2));
    float y2 = __fadd_rn(cy, __fmul_rn(0.5f, h2f));
    x1 = fminf(fmaxf(x1, 0.f), IMGSZ);
    y1 = fminf(fmaxf(y1, 0.f), IMGSZ);
    x2 = fminf(fmaxf(x2, 0.f), IMGSZ);
    y2 = fminf(fmaxf(y2, 0.f), IMGSZ);
    ((float4*)boxes)[(size_t)b * PRE_NMS + i] = make_float4(x1, y1, x2, y2);
  }
}

// ---- IoU tiles: one wave per 64x64 upper-triangle tile --------------------
__global__ __launch_bounds__(64) void iou_tile(
    const float* __restrict__ boxes, u64* __restrict__ maskT) {
  int k = blockIdx.x;       // 0..527 -> (ti <= wj) pair
  int b = blockIdx.y;
  int wj = (int)((sqrtf(8.0f * k + 1.0f) - 1.0f) * 0.5f);
  while ((wj + 1) * (wj + 2) / 2 <= k) ++wj;
  while (wj * (wj + 1) / 2 > k) --wj;
  int ti = k - wj * (wj + 1) / 2;
  int lane = threadIdx.x;
  int i = ti * 64 + lane;
  const float4* bb = (const float4*)boxes + (size_t)b * PRE_NMS;
  __shared__ float4 sbox[64];
  int jg = wj * 64 + lane;
  sbox[lane] = bb[min(jg, PRE_NMS - 1)];
  float4 A4 = bb[min(i, PRE_NMS - 1)];
  __syncthreads();
  float area_a = __fmul_rn(__fsub_rn(A4.z, A4.x), __fsub_rn(A4.w, A4.y));
  u64 m = 0;
  #pragma unroll 8
  for (int jj = 0; jj < 64; ++jj) {
    float4 Bb = sbox[jj];                  // uniform address -> broadcast
    float area_b = __fmul_rn(__fsub_rn(Bb.z, Bb.x), __fsub_rn(Bb.w, Bb.y));
    float ltx = fmaxf(A4.x, Bb.x), lty = fmaxf(A4.y, Bb.y);
    float rbx = fminf(A4.z, Bb.z), rby = fminf(A4.w, Bb.w);
    float iw = fmaxf(__fsub_rn(rbx, ltx), 0.f);
    float ih = fmaxf(__fsub_rn(rby, lty), 0.f);
    float inter = __fmul_rn(iw, ih);
    float denom = __fadd_rn(__fsub_rn(__fadd_rn(area_a, area_b), inter), 1e-9f);
    float iou = inter / denom;
    int j = wj * 64 + jj;
    if (j > i && iou > IOU_T) m |= 1ULL << jj;
  }
  maskT[((size_t)b * NWORDS + wj) * MROWS + i] = m;   // coalesced
}

// ---- NMS scan v5: upper-triangle-only staging, pipelined diag chain, -------
// fused output emit. LDS buf[w*WSTRIDE + r] word-major.
#define WSTRIDE 65
__global__ __launch_bounds__(256, 1) void nms_scan(
    const u64* __restrict__ maskT, const float* __restrict__ boxes,
    const float* __restrict__ logits, float* __restrict__ out) {
  int b = blockIdx.x;
  int tid = threadIdx.x;
  int wave = tid >> 6, lane = tid & 63;
  __shared__ u64 buf[2][NWORDS * WSTRIDE];   // 2 x 16.25 KiB
  __shared__ u64 s_keep[NWORDS];
  __shared__ u64 s_cur;
  if (tid < NWORDS) s_keep[tid] = (tid == NWORDS - 1) ? 0xFFFFULL : ~0ULL;
  const u64* mb = maskT + (size_t)b * NWORDS * MROWS;
  int w = tid >> 3;          // word 0..31
  int sub = tid & 7;         // rows sub*8 .. sub*8+7 of the chunk
  uint4 cur0, cur1, cur2, cur3, nx0, nx1, nx2, nx3;
  {
    const uint4* src = (const uint4*)(mb + (size_t)w * MROWS + sub * 8);
    cur0 = src[0]; cur1 = src[1]; cur2 = src[2]; cur3 = src[3];
  }
  for (int c = 0; c < NWORDS; ++c) {
    int p = c & 1;
    if (w >= c) {                        // only upper-triangle words are used
      u64* dst = &buf[p][w * WSTRIDE + sub * 8];
      dst[0] = ((u64)cur0.y << 32) | cur0.x;  dst[1] = ((u64)cur0.w << 32) | cur0.z;
      dst[2] = ((u64)cur1.y << 32) | cur1.x;  dst[3] = ((u64)cur1.w << 32) | cur1.z;
      dst[4] = ((u64)cur2.y << 32) | cur2.x;  dst[5] = ((u64)cur2.w << 32) | cur2.z;
      dst[6] = ((u64)cur3.y << 32) | cur3.x;  dst[7] = ((u64)cur3.w << 32) | cur3.z;
    }
    __syncthreads();                     // barrier 1: chunk visible in buf[p]
    if (c + 1 < NWORDS && w >= c + 1) {  // prefetch only words >= c+1
      const uint4* src = (const uint4*)(mb + (size_t)w * MROWS + (c + 1) * 64 + sub * 8);
      nx0 = src[0]; nx1 = src[1]; nx2 = src[2]; nx3 = src[3];
    }
    // phase 1: wave 0, software-pipelined 4x16 diag chain (r0/r1 alternate)
    if (wave == 0) {
      const u64* base = &buf[p][c * WSTRIDE];
      u64 r0[16], r1[16];
      #pragma unroll
      for (int t = 0; t < 16; ++t) r0[t] = base[t];
      u64 cur = s_keep[c];
      #pragma unroll
      for (int t = 0; t < 16; ++t) r1[t] = base[16 + t];
      #pragma unroll
      for (int t = 0; t < 16; ++t) {
        u64 bit = (cur >> t) & 1ULL;
        cur &= ~(r0[t] & (0ULL - bit));
      }
      #pragma unroll
      for (int t = 0; t < 16; ++t) r0[t] = base[32 + t];
      #pragma unroll
      for (int t = 0; t < 16; ++t) {
        u64 bit = (cur >> (16 + t)) & 1ULL;
        cur &= ~(r1[t] & (0ULL - bit));
      }
      #pragma unroll
      for (int t = 0; t < 16; ++t) r1[t] = base[48 + t];
      #pragma unroll
      for (int t = 0; t < 16; ++t) {
        u64 bit = (cur >> (32 + t)) & 1ULL;
        cur &= ~(r0[t] & (0ULL - bit));
      }
      #pragma unroll
      for (int t = 0; t < 16; ++t) {
        u64 bit = (cur >> (48 + t)) & 1ULL;
        cur &= ~(r1[t] & (0ULL - bit));
      }
      if (lane == 0) { s_keep[c] = cur; s_cur = cur; }
    }
    __syncthreads();                     // barrier 2: s_cur visible
    // phase 2: words w > c, lane l owns word l (half-wave row split)
    {
      u64 cur = s_cur;
      int l = lane & 31;
      int h = lane >> 5;
      if (l > c) {
        u64 v = 0;
        int base_bb = wave * 16 + h * 8;
        #pragma unroll
        for (int kk = 0; kk < 8; ++kk) {
          int bbr = base_bb + kk;
          u64 bit = (cur >> bbr) & 1ULL;
          v |= buf[p][l * WSTRIDE + bbr] & (0ULL - bit);
        }
        v |= __shfl_xor(v, 32, 64);
        if (lane < 32 && v) atomicAnd(&s_keep[l], ~v);
      }
    }
    cur0 = nx0; cur1 = nx1; cur2 = nx2; cur3 = nx3;
  }
  __syncthreads();
  // fused emit: rank kept boxes, write [box, sigmoid]
  __shared__ int pre[NWORDS];
  if (tid == 0) {
    int acc = 0;
    for (int ww = 0; ww < NWORDS; ++ww) {
      pre[ww] = acc;
      acc += __popcll(s_keep[ww]);
    }
  }
  __syncthreads();
  const float* lg_b = logits + b * PRE_NMS;
  const float4* bx_b = (const float4*)boxes + (size_t)b * PRE_NMS;
  for (int i = tid; i < PRE_NMS; i += 256) {
    u64 wv = s_keep[i >> 6];
    if ((wv >> (i & 63)) & 1) {
      int rank = pre[i >> 6] + __popcll(wv & ((1ULL << (i & 63)) - 1ULL));
      if (rank < POST_NMS) {
        float4 bx = bx_b[i];
        float lg = lg_b[i];
        float e = (float)exp(-(double)lg);
        float pp = 1.0f / (1.0f + e);
        float* o = out + ((size_t)b * POST_NMS + rank) * 5;
        o[0] = bx.x; o[1] = bx.y; o[2] = bx.z; o[3] = bx.w; o[4] = pp;
      }
    }
  }
}

extern "C" void kernel_launch(void* const* d_in, const int* in_sizes, int n_in,
                              void* d_out, int out_size, void* d_ws, size_t ws_size,
                              hipStream_t stream) {
  const float* scores  = (const float*)d_in[0];
  const float* deltas  = (const float*)d_in[1];
  const float* anchors = (const float*)d_in[2];
  int A = in_sizes[2] / 4;          // 159882
  int B = in_sizes[0] / A;          // 16

  char* ws = (char*)d_ws;
  size_t off = 0;
  auto alloc = [&](size_t bytes) {
    void* p = ws + off;
    off += (bytes + 255) & ~(size_t)255;
    return p;
  };
  unsigned* ghist    = (unsigned*)alloc((size_t)B * NBINS * 4);
  int*      cand_cnt = (int*)alloc((size_t)B * 4);
  size_t zero_bytes = off;
  int*      T1       = (int*)alloc((size_t)B * 4);
  u64*      cand     = (u64*)alloc((size_t)B * CAP * 8);
  float*    topk_lg  = (float*)alloc((size_t)B * PRE_NMS * 4);
  float*    boxes    = (float*)alloc((size_t)B * PRE_NMS * 16);
  u64*      maskT    = (u64*)alloc((size_t)B * NWORDS * MROWS * 8);

  hipMemsetAsync(d_out, 0, (size_t)out_size * 4, stream);
  hipMemsetAsync(ws, 0, zero_bytes, stream);

  hist_kernel<<<dim3(B, NSLICE), 256, 0, stream>>>(scores, A, ghist);
  thresh1_kernel<<<B, 1024, 0, stream>>>(ghist, T1);
  compact_kernel<<<dim3(B, NSLICE), 256, 0, stream>>>(scores, A, T1, cand, cand_cnt);
  refine_sort_kernel<<<B, 1024, 0, stream>>>(cand, cand_cnt, T1, deltas, anchors, A,
                                             boxes, topk_lg);
  int ntiles = NWORDS * (NWORDS + 1) / 2;   // 528 upper-triangle tiles
  iou_tile<<<dim3(ntiles, B), 64, 0, stream>>>(boxes, maskT);
  nms_scan<<<B, 256, 0, stream>>>(maskT, boxes, topk_lg, (float*)d_out);
}